// Round 25
// baseline (287.826 us; speedup 1.0000x reference)
//
#include <hip/hip_runtime.h>

// GCN 2-layer + mean-pool + linear head, f32.
// Round 25: traffic deletion on proven code (r24 = 236.2us, all kernels
// at/near their structural floors except latency-pinned gemm1).
//   - agg_pool: fuse layer-2 aggregation + mean-pool prep. Block's 8
//     node-rows staged in 2KB LDS; 64-thread run-length reduction
//     (batch sorted) -> ~1-2 atomics/column/block. Deletes agg2's 25.6MB
//     write + pool's 25.6MB read + batch re-read + one launch.
//   - CSR pairs packed to one int: (dst&255)<<24 | src (src < 2^17).
//     Halves scatter write / build read.
// gemm1 (counted-vmcnt DMA, r22), gemm2 (bf16-A, r24), agg1 (bf16 in/out),
// CSR build structure, init, final unchanged.

#define NN 100000
#define NG 128
#define BNODES 256
#define NBUK ((NN + BNODES - 1) / BNODES)   // 391
#define BCAP 6144

typedef __attribute__((ext_vector_type(8))) short short8;
typedef __attribute__((ext_vector_type(8))) unsigned short u16x8;
typedef __attribute__((ext_vector_type(4))) float f32x4;

__device__ __forceinline__ unsigned short f2bf(float f) {
    union { float f; unsigned u; } v; v.f = f;
    unsigned r = v.u + 0x7fffu + ((v.u >> 16) & 1u);  // round-nearest-even
    return (unsigned short)(r >> 16);
}
__device__ __forceinline__ float bf2f(unsigned short h) {
    union { unsigned u; float f; } v; v.u = ((unsigned)h) << 16;
    return v.f;
}

__device__ __forceinline__ void gload_lds16(const void* g, void* l) {
    __builtin_amdgcn_global_load_lds(
        (const __attribute__((address_space(1))) void*)g,
        (__attribute__((address_space(3))) void*)l, 16, 0, 0);
}

// zero bcnt + pooled + cnt in one launch
__global__ __launch_bounds__(256) void init_kernel(int* __restrict__ bcnt,
                                                   float* __restrict__ pooled,
                                                   float* __restrict__ cnt) {
    const int i = blockIdx.x * 256 + threadIdx.x;
    if (i < NBUK) bcnt[i] = 0;
    if (i < NG * 64) pooled[i] = 0.f;
    if (i < NG) cnt[i] = 0.f;
}

// ---- pass 1: bucket edges by dst>>8; pairs packed (dst&255)<<24 | src ----
__global__ __launch_bounds__(256) void bucket_scatter(const int* __restrict__ src,
                                                      const int* __restrict__ dst,
                                                      int* __restrict__ bcnt,
                                                      int* __restrict__ pairs, int E) {
    __shared__ int hist[NBUK];
    __shared__ int lbase[NBUK];
    __shared__ int lfill[NBUK];
    const int t = threadIdx.x;
    const int chunk = (E + gridDim.x - 1) / gridDim.x;
    const int lo = blockIdx.x * chunk;
    const int hi = min(E, lo + chunk);
    for (int b = t; b < NBUK; b += 256) { hist[b] = 0; lfill[b] = 0; }
    __syncthreads();
    for (int i = lo + t; i < hi; i += 256)
        atomicAdd(&hist[dst[i] >> 8], 1);
    __syncthreads();
    for (int b = t; b < NBUK; b += 256)
        lbase[b] = hist[b] ? atomicAdd(&bcnt[b], hist[b]) : 0;
    __syncthreads();
    for (int i = lo + t; i < hi; i += 256) {
        const int s = src[i], d = dst[i];
        const int b = d >> 8;
        const int off = atomicAdd(&lfill[b], 1);
        pairs[(size_t)b * BCAP + lbase[b] + off] = ((d & 255) << 24) | s;
    }
}

// ---- pass 2a: exclusive scan of bucket counts -> bucket bases ----
__global__ __launch_bounds__(512) void bucket_scan(const int* __restrict__ bcnt,
                                                   int* __restrict__ bbase,
                                                   int* __restrict__ rowptr,
                                                   int N, int E) {
    __shared__ int sm[512];
    const int t = threadIdx.x;
    sm[t] = (t < NBUK) ? bcnt[t] : 0;
    __syncthreads();
    for (int d = 1; d < 512; d <<= 1) {
        int a = (t >= d) ? sm[t - d] : 0;
        __syncthreads();
        sm[t] += a;
        __syncthreads();
    }
    if (t <= NBUK) bbase[t] = (t == 0) ? 0 : sm[t - 1];
    if (t == 0) rowptr[N] = E;
}

// ---- pass 2b: per-bucket node histogram + scan -> rowptr/dis, col fill ----
__global__ __launch_bounds__(256) void bucket_build(const int* __restrict__ pairs,
                                                    const int* __restrict__ bcnt,
                                                    const int* __restrict__ bbase,
                                                    int* __restrict__ rowptr,
                                                    float* __restrict__ dis,
                                                    int* __restrict__ col, int N) {
    __shared__ int cnt[BNODES];
    __shared__ int sm[BNODES];
    __shared__ int pref[BNODES];
    __shared__ int fillc[BNODES];
    const int b = blockIdx.x;
    const int t = threadIdx.x;
    const int nbase = b * BNODES;
    const int ecnt = bcnt[b];
    const int* ep = pairs + (size_t)b * BCAP;
    const int gbase = bbase[b];

    cnt[t] = 0;
    fillc[t] = 0;
    __syncthreads();
    for (int i = t; i < ecnt; i += 256)
        atomicAdd(&cnt[((unsigned)ep[i]) >> 24], 1);
    __syncthreads();
    sm[t] = cnt[t];
    __syncthreads();
    for (int d = 1; d < 256; d <<= 1) {
        int a = (t >= d) ? sm[t - d] : 0;
        __syncthreads();
        sm[t] += a;
        __syncthreads();
    }
    pref[t] = sm[t] - cnt[t];
    const int node = nbase + t;
    if (node < N) {
        rowptr[node] = gbase + pref[t];
        dis[node] = rsqrtf((float)cnt[t] + 1.0f);
    }
    __syncthreads();
    for (int i = t; i < ecnt; i += 256) {
        const int p = ep[i];
        const int d = ((unsigned)p) >> 24;
        const int pos = gbase + pref[d] + atomicAdd(&fillc[d], 1);
        col[pos] = p & 0xFFFFFF;
    }
}

// One-time weight pack: W [K][BN] f32 -> hi/lo bf16 in MFMA fragment order.
__global__ __launch_bounds__(256) void pack_w(const float* __restrict__ W,
                                              unsigned short* __restrict__ packH,
                                              unsigned short* __restrict__ packL,
                                              int K, int BN) {
    const int idx = blockIdx.x * blockDim.x + threadIdx.x;
    if (idx >= K * BN) return;
    const int e = idx & 7;
    const int l = (idx >> 3) & 63;
    const int rest = idx >> 9;  // ks*NF + nf
    const int NF = BN >> 4;
    const int nf = rest % NF;
    const int ks = rest / NF;
    const int n = nf * 16 + (l & 15);
    const int k = ks * 32 + ((l >> 4) & 3) * 8 + e;
    const float v = W[(size_t)k * BN + n];
    const unsigned short h = f2bf(v);
    packH[idx] = h;
    packL[idx] = f2bf(v - bf2f(h));
}

// MFMA GEMM (layer 1): f32 A, 4-buffer global_load_lds pipeline, counted
// vmcnt, raw s_barrier. BM=64, BK=32. A consumed as bf16-hi; W hi/lo.
template <int BN, int K>
__global__ __launch_bounds__(256) void gemm_mfma(const float* __restrict__ A,
                                                 const unsigned short* __restrict__ WpH,
                                                 const unsigned short* __restrict__ WpL,
                                                 const float* __restrict__ scale,
                                                 unsigned short* __restrict__ Out,
                                                 int N) {
    constexpr int BM = 64;
    constexpr int NK = K / 32;               // 12
    constexpr int WROWS = (BN == 128) ? 2 : 4;
    constexpr int WCOLS = (BN == 128) ? 2 : 1;
    constexpr int WTM = BM / WROWS;
    constexpr int MF = WTM / 16;
    constexpr int NFW = (BN / WCOLS) / 16;
    constexpr int NFB = BN / 16;

    __shared__ float AsF[4][4][16][32];  // 32 KB

    const int t = threadIdx.x;
    const int wid = t >> 6, lane = t & 63;
    const int wr = wid / WCOLS, wc = wid % WCOLS;
    const int r0 = blockIdx.x * BM;

    const int dmarow0 = min(r0 + wid * 16 + (lane >> 3), NN - 1);
    const int dmarow1 = min(r0 + wid * 16 + 8 + (lane >> 3), NN - 1);
    const float* dmap0 = A + (size_t)dmarow0 * K + (lane & 7) * 4;
    const float* dmap1 = A + (size_t)dmarow1 * K + (lane & 7) * 4;

    auto stageA = [&](int buf, int ks) {
        gload_lds16(dmap0 + ks * 32, &AsF[buf][wid][0][0]);
        gload_lds16(dmap1 + ks * 32, &AsF[buf][wid][8][0]);
    };
    auto loadB = [&](int ks, short8* bH, short8* bL) {
#pragma unroll
        for (int n = 0; n < NFW; ++n) {
            const int nfg = wc * NFW + n;
            const int base = ((ks * NFB + nfg) * 64 + lane) * 8;
            bH[n] = *(const short8*)&WpH[base];
            bL[n] = *(const short8*)&WpL[base];
        }
    };

    f32x4 acc[MF][NFW];
#pragma unroll
    for (int m = 0; m < MF; ++m)
#pragma unroll
        for (int n = 0; n < NFW; ++n) acc[m][n] = (f32x4){0.f, 0.f, 0.f, 0.f};

    short8 bHc[NFW], bLc[NFW];
    loadB(0, bHc, bLc);
    stageA(0, 0);
    if (NK > 1) stageA(1, 1);
    if (NK > 2) stageA(2, 2);

#pragma unroll
    for (int ks = 0; ks < NK; ++ks) {
        if (ks == NK - 1) {
            asm volatile("s_waitcnt vmcnt(0)" ::: "memory");
        } else {
            asm volatile("s_waitcnt vmcnt(4)" ::: "memory");
        }
        __builtin_amdgcn_s_barrier();
        short8 bHn[NFW], bLn[NFW];
        if (ks + 1 < NK) loadB(ks + 1, bHn, bLn);
        if (ks + 3 < NK) stageA((ks + 3) & 3, ks + 3);
        const int cur = ks & 3;
#pragma unroll
        for (int m = 0; m < MF; ++m) {
            const int mf = wr * MF + m;
            const float* fp = &AsF[cur][mf][lane & 15][(lane >> 4) * 8];
            const f32x4 f0 = *(const f32x4*)fp;
            const f32x4 f1 = *(const f32x4*)(fp + 4);
            short8 aH;
            aH[0] = (short)f2bf(f0[0]);
            aH[1] = (short)f2bf(f0[1]);
            aH[2] = (short)f2bf(f0[2]);
            aH[3] = (short)f2bf(f0[3]);
            aH[4] = (short)f2bf(f1[0]);
            aH[5] = (short)f2bf(f1[1]);
            aH[6] = (short)f2bf(f1[2]);
            aH[7] = (short)f2bf(f1[3]);
#pragma unroll
            for (int n = 0; n < NFW; ++n) {
                acc[m][n] = __builtin_amdgcn_mfma_f32_16x16x32_bf16(aH, bHc[n], acc[m][n], 0, 0, 0);
                acc[m][n] = __builtin_amdgcn_mfma_f32_16x16x32_bf16(aH, bLc[n], acc[m][n], 0, 0, 0);
            }
        }
        if (ks + 1 < NK) {
#pragma unroll
            for (int n = 0; n < NFW; ++n) {
                bHc[n] = bHn[n];
                bLc[n] = bLn[n];
            }
        }
    }

#pragma unroll
    for (int m = 0; m < MF; ++m) {
        const int row0 = r0 + wr * WTM + m * 16 + ((lane >> 4) << 2);
        float sc[4];
#pragma unroll
        for (int r = 0; r < 4; ++r) sc[r] = (row0 + r < N) ? scale[row0 + r] : 0.f;
#pragma unroll
        for (int n = 0; n < NFW; ++n) {
            const int cn = wc * (NFW * 16) + n * 16 + (lane & 15);
#pragma unroll
            for (int r = 0; r < 4; ++r) {
                if (row0 + r < N)
                    Out[(size_t)(row0 + r) * BN + cn] = f2bf(acc[m][n][r] * sc[r]);
            }
        }
    }
}

// MFMA GEMM (layer 2): bf16 A, counted-vmcnt 4-buffer DMA pipeline.
// 1 DMA/wave/tile. vmcnt: iter0=2, mid=4, last=0 (r24 audit).
template <int BN, int K>
__global__ __launch_bounds__(256) void gemm_mfma_b(const unsigned short* __restrict__ A,
                                                   const unsigned short* __restrict__ WpH,
                                                   const unsigned short* __restrict__ WpL,
                                                   const float* __restrict__ scale,
                                                   unsigned short* __restrict__ Out,
                                                   int N) {
    constexpr int BM = 64;
    constexpr int NK = K / 32;               // 4
    constexpr int WROWS = 4;
    constexpr int WTM = BM / WROWS;          // 16
    constexpr int NFW = BN / 16;             // 4
    constexpr int NFB = BN / 16;

    __shared__ unsigned short AsB[4][4][16][32];  // 16 KB

    const int t = threadIdx.x;
    const int wid = t >> 6, lane = t & 63;
    const int wr = wid;
    const int r0 = blockIdx.x * BM;

    const int dmarow = min(r0 + wid * 16 + (lane >> 2), NN - 1);
    const unsigned short* dmap = A + (size_t)dmarow * K + (lane & 3) * 8;

    auto stageA = [&](int buf, int ks) {
        gload_lds16(dmap + ks * 32, &AsB[buf][wid][0][0]);
    };
    auto loadB = [&](int ks, short8* bH, short8* bL) {
#pragma unroll
        for (int n = 0; n < NFW; ++n) {
            const int base = ((ks * NFB + n) * 64 + lane) * 8;
            bH[n] = *(const short8*)&WpH[base];
            bL[n] = *(const short8*)&WpL[base];
        }
    };

    f32x4 acc[NFW];
#pragma unroll
    for (int n = 0; n < NFW; ++n) acc[n] = (f32x4){0.f, 0.f, 0.f, 0.f};

    short8 bHc[NFW], bLc[NFW];
    loadB(0, bHc, bLc);
    stageA(0, 0);
    if (NK > 1) stageA(1, 1);
    if (NK > 2) stageA(2, 2);

#pragma unroll
    for (int ks = 0; ks < NK; ++ks) {
        if (ks == NK - 1) {
            asm volatile("s_waitcnt vmcnt(0)" ::: "memory");
        } else if (ks == 0) {
            asm volatile("s_waitcnt vmcnt(2)" ::: "memory");
        } else {
            asm volatile("s_waitcnt vmcnt(4)" ::: "memory");
        }
        __builtin_amdgcn_s_barrier();
        short8 bHn[NFW], bLn[NFW];
        if (ks + 1 < NK) loadB(ks + 1, bHn, bLn);
        if (ks + 3 < NK) stageA((ks + 3) & 3, ks + 3);
        const int cur = ks & 3;
        const short8 aH = *(const short8*)&AsB[cur][wr][lane & 15][(lane >> 4) * 8];
#pragma unroll
        for (int n = 0; n < NFW; ++n) {
            acc[n] = __builtin_amdgcn_mfma_f32_16x16x32_bf16(aH, bHc[n], acc[n], 0, 0, 0);
            acc[n] = __builtin_amdgcn_mfma_f32_16x16x32_bf16(aH, bLc[n], acc[n], 0, 0, 0);
        }
        if (ks + 1 < NK) {
#pragma unroll
            for (int n = 0; n < NFW; ++n) {
                bHc[n] = bHn[n];
                bLc[n] = bLn[n];
            }
        }
    }

    const int row0 = r0 + wr * WTM + ((lane >> 4) << 2);
    float sc[4];
#pragma unroll
    for (int r = 0; r < 4; ++r) sc[r] = (row0 + r < N) ? scale[row0 + r] : 0.f;
#pragma unroll
    for (int n = 0; n < NFW; ++n) {
        const int cn = n * 16 + (lane & 15);
#pragma unroll
        for (int r = 0; r < 4; ++r) {
            if (row0 + r < N)
                Out[(size_t)(row0 + r) * BN + cn] = f2bf(acc[n][r] * sc[r]);
        }
    }
}

// Layer-1 aggregation (COLS=128), bf16 in/out (r24 proven).
__global__ __launch_bounds__(256) void agg_gather128(const int* __restrict__ rowptr,
                                                     const int* __restrict__ col,
                                                     const float* __restrict__ dis,
                                                     const unsigned short* __restrict__ Hs,
                                                     const float* __restrict__ bias,
                                                     unsigned short* __restrict__ Out,
                                                     int N) {
    constexpr int COLS = 128;
    constexpr int LPN = 64;
    constexpr int LPR = COLS / 8;   // 16
    constexpr int NSG = 4;
    const int gw = (int)((blockIdx.x * blockDim.x + threadIdx.x) >> 6);
    const int lane = threadIdx.x & 63;
    const int nl = lane;
    const int esub = nl / LPR;
    const int sl = nl % LPR;
    const int node = gw;
    const int lgbase = 0;

    float acc[8];
#pragma unroll
    for (int k = 0; k < 8; ++k) acc[k] = 0.f;

    int base = 0, len = 0;
    const int nodec = (node < N) ? node : 0;
    if (node < N) {
        base = rowptr[node];
        len = rowptr[node + 1] - base;
    }

    for (int j0 = 0; j0 < len; j0 += LPN) {
        const int remain = min(LPN, len - j0);
        const int sidx = (nl < remain) ? col[base + j0 + nl] : nodec;
        const int qtr = (remain + NSG - 1) / NSG;
        const int off = esub * qtr;
        int u = 0;
        for (; u + 8 <= qtr; u += 8) {
            u16x8 hv[8];
            float wv[8];
#pragma unroll
            for (int b = 0; b < 8; ++b) {
                const int idx = off + u + b;
                const int s = __shfl(sidx, lgbase + idx);
                wv[b] = (idx < remain) ? 1.f : 0.f;
                hv[b] = *(const u16x8*)(Hs + (size_t)s * COLS + sl * 8);
            }
#pragma unroll
            for (int b = 0; b < 8; ++b)
#pragma unroll
                for (int k = 0; k < 8; ++k)
                    acc[k] = fmaf(bf2f(hv[b][k]), wv[b], acc[k]);
        }
        for (; u + 4 <= qtr; u += 4) {
            u16x8 hv[4];
            float wv[4];
#pragma unroll
            for (int b = 0; b < 4; ++b) {
                const int idx = off + u + b;
                const int s = __shfl(sidx, lgbase + idx);
                wv[b] = (idx < remain) ? 1.f : 0.f;
                hv[b] = *(const u16x8*)(Hs + (size_t)s * COLS + sl * 8);
            }
#pragma unroll
            for (int b = 0; b < 4; ++b)
#pragma unroll
                for (int k = 0; k < 8; ++k)
                    acc[k] = fmaf(bf2f(hv[b][k]), wv[b], acc[k]);
        }
        for (; u < qtr; ++u) {
            const int idx = off + u;
            const int s = __shfl(sidx, lgbase + idx);
            const float w = (idx < remain) ? 1.f : 0.f;
            const u16x8 hv = *(const u16x8*)(Hs + (size_t)s * COLS + sl * 8);
#pragma unroll
            for (int k = 0; k < 8; ++k)
                acc[k] = fmaf(bf2f(hv[k]), w, acc[k]);
        }
    }

#pragma unroll
    for (int k = 0; k < 8; ++k) {
        acc[k] += __shfl_xor(acc[k], LPR);
        acc[k] += __shfl_xor(acc[k], 2 * LPR);
    }

    if (node < N && esub == 0) {
        const float dd = dis[node];
        const u16x8 hsb = *(const u16x8*)(Hs + (size_t)node * COLS + sl * 8);
        u16x8 ob;
#pragma unroll
        for (int k = 0; k < 8; ++k)
            ob[k] = f2bf(fmaxf(fmaf(acc[k] + bf2f(hsb[k]), dd, bias[sl * 8 + k]), 0.f));
        *(u16x8*)(Out + (size_t)node * COLS + sl * 8) = ob;
    }
}

// Layer-2 aggregation (COLS=64) FUSED with mean-pool accumulation.
// Block = 8 nodes (4 waves x 2). After gather epilogue, node rows staged
// in LDS; 64-thread run-length reduction (batch sorted) -> ~1-2 atomics
// per column per block into pooled/cnt.
__global__ __launch_bounds__(256) void agg_pool(const int* __restrict__ rowptr,
                                                const int* __restrict__ col,
                                                const float* __restrict__ dis,
                                                const unsigned short* __restrict__ Hs,
                                                const float* __restrict__ bias,
                                                const int* __restrict__ batch,
                                                float* __restrict__ pooled,
                                                float* __restrict__ cnt, int N) {
    constexpr int COLS = 64;
    constexpr int NPW = 2;
    constexpr int LPN = 32;
    constexpr int LPR = COLS / 8;   // 8
    constexpr int NSG = 4;

    __shared__ float pbuf[8][64];
    __shared__ int pg[8];

    const int t = threadIdx.x;
    const int wid = t >> 6;
    const int gw = (int)blockIdx.x * 4 + wid;
    const int lane = t & 63;
    const int sub = lane / LPN;
    const int nl = lane % LPN;
    const int esub = nl / LPR;
    const int sl = nl % LPR;
    const int node = gw * NPW + sub;
    const int slot = wid * 2 + sub;
    const int lgbase = sub * LPN;

    float acc[8];
#pragma unroll
    for (int k = 0; k < 8; ++k) acc[k] = 0.f;

    int base = 0, len = 0;
    const int nodec = (node < N) ? node : 0;
    if (node < N) {
        base = rowptr[node];
        len = rowptr[node + 1] - base;
    }

    for (int j0 = 0; j0 < len; j0 += LPN) {
        const int remain = min(LPN, len - j0);
        const int sidx = (nl < remain) ? col[base + j0 + nl] : nodec;
        const int qtr = (remain + NSG - 1) / NSG;
        const int off = esub * qtr;
        int u = 0;
        for (; u + 8 <= qtr; u += 8) {
            u16x8 hv[8];
            float wv[8];
#pragma unroll
            for (int b = 0; b < 8; ++b) {
                const int idx = off + u + b;
                const int s = __shfl(sidx, lgbase + idx);
                wv[b] = (idx < remain) ? 1.f : 0.f;
                hv[b] = *(const u16x8*)(Hs + (size_t)s * COLS + sl * 8);
            }
#pragma unroll
            for (int b = 0; b < 8; ++b)
#pragma unroll
                for (int k = 0; k < 8; ++k)
                    acc[k] = fmaf(bf2f(hv[b][k]), wv[b], acc[k]);
        }
        for (; u + 4 <= qtr; u += 4) {
            u16x8 hv[4];
            float wv[4];
#pragma unroll
            for (int b = 0; b < 4; ++b) {
                const int idx = off + u + b;
                const int s = __shfl(sidx, lgbase + idx);
                wv[b] = (idx < remain) ? 1.f : 0.f;
                hv[b] = *(const u16x8*)(Hs + (size_t)s * COLS + sl * 8);
            }
#pragma unroll
            for (int b = 0; b < 4; ++b)
#pragma unroll
                for (int k = 0; k < 8; ++k)
                    acc[k] = fmaf(bf2f(hv[b][k]), wv[b], acc[k]);
        }
        for (; u < qtr; ++u) {
            const int idx = off + u;
            const int s = __shfl(sidx, lgbase + idx);
            const float w = (idx < remain) ? 1.f : 0.f;
            const u16x8 hv = *(const u16x8*)(Hs + (size_t)s * COLS + sl * 8);
#pragma unroll
            for (int k = 0; k < 8; ++k)
                acc[k] = fmaf(bf2f(hv[k]), w, acc[k]);
        }
    }

#pragma unroll
    for (int k = 0; k < 8; ++k) {
        acc[k] += __shfl_xor(acc[k], LPR);
        acc[k] += __shfl_xor(acc[k], 2 * LPR);
    }

    // stage this node's output row in LDS (value-safe for node >= N)
    if (esub == 0) {
        const float dd = dis[nodec];
        const u16x8 hsb = *(const u16x8*)(Hs + (size_t)nodec * COLS + sl * 8);
#pragma unroll
        for (int k = 0; k < 8; ++k)
            pbuf[slot][sl * 8 + k] =
                fmaxf(fmaf(acc[k] + bf2f(hsb[k]), dd, bias[sl * 8 + k]), 0.f);
        if (sl == 0) pg[slot] = (node < N) ? batch[node] : -1;
    }
    __syncthreads();

    // run-length pooled accumulation: thread t<64 owns column t
    if (t < 64) {
        int curg = -2;
        float sum = 0.f, csum = 0.f;
#pragma unroll
        for (int s = 0; s < 8; ++s) {
            const int g = pg[s];
            if (g >= 0) {
                if (g != curg) {
                    if (curg >= 0) {
                        atomicAdd(&pooled[curg * 64 + t], sum);
                        if (t == 0) atomicAdd(&cnt[curg], csum);
                    }
                    curg = g;
                    sum = 0.f;
                    csum = 0.f;
                }
                sum += pbuf[s][t];
                csum += 1.f;
            }
        }
        if (curg >= 0) {
            atomicAdd(&pooled[curg * 64 + t], sum);
            if (t == 0) atomicAdd(&cnt[curg], csum);
        }
    }
}

__global__ __launch_bounds__(256) void final_kernel(const float* __restrict__ pooled,
                                                    const float* __restrict__ cnt,
                                                    const float* __restrict__ Wlin,
                                                    const float* __restrict__ blin,
                                                    float* __restrict__ out) {
    const int t = threadIdx.x;
    const int g = t >> 1, o = t & 1;
    const float inv = 1.0f / fmaxf(cnt[g], 1.0f);
    float s = 0.f;
#pragma unroll
    for (int j = 0; j < 64; ++j) s = fmaf(pooled[g * 64 + j], Wlin[j * 2 + o], s);
    out[t] = s * inv + blin[o];
}

extern "C" void kernel_launch(void* const* d_in, const int* in_sizes, int n_in,
                              void* d_out, int out_size, void* d_ws, size_t ws_size,
                              hipStream_t stream) {
    const float* x     = (const float*)d_in[0];
    const int*   edge  = (const int*)d_in[1];
    const int*   batch = (const int*)d_in[2];
    const float* W1    = (const float*)d_in[3];
    const float* b1    = (const float*)d_in[4];
    const float* W2    = (const float*)d_in[5];
    const float* b2    = (const float*)d_in[6];
    const float* Wlin  = (const float*)d_in[7];
    const float* blin  = (const float*)d_in[8];
    float* out = (float*)d_out;

    const int N = NN;
    const int E = in_sizes[1] / 2;
    const int* src = edge;
    const int* dst = edge + E;

    char* ws = (char*)d_ws;
    size_t off = 0;
    auto alloc = [&](size_t bytes) -> void* {
        void* p = ws + off;
        off += (bytes + 511) & ~(size_t)511;
        return p;
    };
    float* dis    = (float*)alloc((size_t)N * 4);
    int*   rowptr = (int*)alloc((size_t)(N + 1) * 4);
    int*   bcnt   = (int*)alloc((size_t)NBUK * 4);
    int*   bbase  = (int*)alloc((size_t)(NBUK + 1) * 4);
    int*   col    = (int*)alloc((size_t)E * 4);                 // 6.4 MB
    int*   pairs  = (int*)alloc((size_t)NBUK * BCAP * 4);       // 9.6 MB (packed)
    unsigned short* w1h = (unsigned short*)alloc((size_t)384 * 128 * 2);
    unsigned short* w1l = (unsigned short*)alloc((size_t)384 * 128 * 2);
    unsigned short* w2h = (unsigned short*)alloc((size_t)128 * 64 * 2);
    unsigned short* w2l = (unsigned short*)alloc((size_t)128 * 64 * 2);
    unsigned short* h1bf   = (unsigned short*)alloc((size_t)N * 128 * 2);  // 25.6 MB
    unsigned short* agg1bf = (unsigned short*)alloc((size_t)N * 128 * 2);  // 25.6 MB
    float* pooled = (float*)alloc((size_t)NG * 64 * 4);
    float* cnt    = (float*)alloc((size_t)NG * 4);
    unsigned short* h2bf = h1bf;   // h1bf dead after agg1

    // zero bcnt/pooled/cnt
    init_kernel<<<(NG * 64 + 255) / 256, 256, 0, stream>>>(bcnt, pooled, cnt);

    // weight packing (tiny, once per call)
    pack_w<<<(384 * 128 + 255) / 256, 256, 0, stream>>>(W1, w1h, w1l, 384, 128);
    pack_w<<<(128 * 64 + 255) / 256, 256, 0, stream>>>(W2, w2h, w2l, 128, 64);

    // CSR build via bucketed counting sort (packed pairs)
    bucket_scatter<<<512, 256, 0, stream>>>(src, dst, bcnt, pairs, E);
    bucket_scan<<<1, 512, 0, stream>>>(bcnt, bbase, rowptr, N, E);
    bucket_build<<<NBUK, 256, 0, stream>>>(pairs, bcnt, bbase, rowptr, dis, col, N);

    const int gblocks = (N + 63) / 64;  // 1563
    // layer 1
    gemm_mfma<128, 384><<<gblocks, 256, 0, stream>>>(x, w1h, w1l, dis, h1bf, N);
    agg_gather128<<<(N + 3) / 4, 256, 0, stream>>>(rowptr, col, dis, h1bf, b1, agg1bf, N);

    // layer 2 (bf16-A gemm; aggregation fused with pooling)
    gemm_mfma_b<64, 128><<<gblocks, 256, 0, stream>>>(agg1bf, w2h, w2l, dis, h2bf, N);
    agg_pool<<<(N + 7) / 8, 256, 0, stream>>>(rowptr, col, dis, h2bf, b2, batch,
                                              pooled, cnt, N);

    // head
    final_kernel<<<1, 256, 0, stream>>>(pooled, cnt, Wlin, blin, out);
}

// Round 26
// 234.897 us; speedup vs baseline: 1.2253x; 1.2253x over previous
//
#include <hip/hip_runtime.h>

// GCN 2-layer + mean-pool + linear head, f32.
// Round 26: revert r25's agg+pool fusion (regressed 236->288: ~1M atomics
// hammering 512 cache lines of the 32KB pooled buffer, ~2000 serialized
// RMWs/line; standalone pool amortizes 32 rows/atomic). Restore the r24
// structure (best: 236.2us), keeping r25's one safe win: packed CSR pairs
// ((dst&255)<<24|src, halves scatter write / build read; correctness
// proven by r25's passing absmax).

#define NN 100000
#define NG 128
#define BNODES 256
#define NBUK ((NN + BNODES - 1) / BNODES)   // 391
#define BCAP 6144

typedef __attribute__((ext_vector_type(8))) short short8;
typedef __attribute__((ext_vector_type(8))) unsigned short u16x8;
typedef __attribute__((ext_vector_type(4))) float f32x4;

__device__ __forceinline__ unsigned short f2bf(float f) {
    union { float f; unsigned u; } v; v.f = f;
    unsigned r = v.u + 0x7fffu + ((v.u >> 16) & 1u);  // round-nearest-even
    return (unsigned short)(r >> 16);
}
__device__ __forceinline__ float bf2f(unsigned short h) {
    union { unsigned u; float f; } v; v.u = ((unsigned)h) << 16;
    return v.f;
}

__device__ __forceinline__ void gload_lds16(const void* g, void* l) {
    __builtin_amdgcn_global_load_lds(
        (const __attribute__((address_space(1))) void*)g,
        (__attribute__((address_space(3))) void*)l, 16, 0, 0);
}

// zero bcnt + pooled + cnt in one launch
__global__ __launch_bounds__(256) void init_kernel(int* __restrict__ bcnt,
                                                   float* __restrict__ pooled,
                                                   float* __restrict__ cnt) {
    const int i = blockIdx.x * 256 + threadIdx.x;
    if (i < NBUK) bcnt[i] = 0;
    if (i < NG * 64) pooled[i] = 0.f;
    if (i < NG) cnt[i] = 0.f;
}

// ---- pass 1: bucket edges by dst>>8; pairs packed (dst&255)<<24 | src ----
__global__ __launch_bounds__(256) void bucket_scatter(const int* __restrict__ src,
                                                      const int* __restrict__ dst,
                                                      int* __restrict__ bcnt,
                                                      int* __restrict__ pairs, int E) {
    __shared__ int hist[NBUK];
    __shared__ int lbase[NBUK];
    __shared__ int lfill[NBUK];
    const int t = threadIdx.x;
    const int chunk = (E + gridDim.x - 1) / gridDim.x;
    const int lo = blockIdx.x * chunk;
    const int hi = min(E, lo + chunk);
    for (int b = t; b < NBUK; b += 256) { hist[b] = 0; lfill[b] = 0; }
    __syncthreads();
    for (int i = lo + t; i < hi; i += 256)
        atomicAdd(&hist[dst[i] >> 8], 1);
    __syncthreads();
    for (int b = t; b < NBUK; b += 256)
        lbase[b] = hist[b] ? atomicAdd(&bcnt[b], hist[b]) : 0;
    __syncthreads();
    for (int i = lo + t; i < hi; i += 256) {
        const int s = src[i], d = dst[i];
        const int b = d >> 8;
        const int off = atomicAdd(&lfill[b], 1);
        pairs[(size_t)b * BCAP + lbase[b] + off] = ((d & 255) << 24) | s;
    }
}

// ---- pass 2a: exclusive scan of bucket counts -> bucket bases ----
__global__ __launch_bounds__(512) void bucket_scan(const int* __restrict__ bcnt,
                                                   int* __restrict__ bbase,
                                                   int* __restrict__ rowptr,
                                                   int N, int E) {
    __shared__ int sm[512];
    const int t = threadIdx.x;
    sm[t] = (t < NBUK) ? bcnt[t] : 0;
    __syncthreads();
    for (int d = 1; d < 512; d <<= 1) {
        int a = (t >= d) ? sm[t - d] : 0;
        __syncthreads();
        sm[t] += a;
        __syncthreads();
    }
    if (t <= NBUK) bbase[t] = (t == 0) ? 0 : sm[t - 1];
    if (t == 0) rowptr[N] = E;
}

// ---- pass 2b: per-bucket node histogram + scan -> rowptr/dis, col fill ----
__global__ __launch_bounds__(256) void bucket_build(const int* __restrict__ pairs,
                                                    const int* __restrict__ bcnt,
                                                    const int* __restrict__ bbase,
                                                    int* __restrict__ rowptr,
                                                    float* __restrict__ dis,
                                                    int* __restrict__ col, int N) {
    __shared__ int cnt[BNODES];
    __shared__ int sm[BNODES];
    __shared__ int pref[BNODES];
    __shared__ int fillc[BNODES];
    const int b = blockIdx.x;
    const int t = threadIdx.x;
    const int nbase = b * BNODES;
    const int ecnt = bcnt[b];
    const int* ep = pairs + (size_t)b * BCAP;
    const int gbase = bbase[b];

    cnt[t] = 0;
    fillc[t] = 0;
    __syncthreads();
    for (int i = t; i < ecnt; i += 256)
        atomicAdd(&cnt[((unsigned)ep[i]) >> 24], 1);
    __syncthreads();
    sm[t] = cnt[t];
    __syncthreads();
    for (int d = 1; d < 256; d <<= 1) {
        int a = (t >= d) ? sm[t - d] : 0;
        __syncthreads();
        sm[t] += a;
        __syncthreads();
    }
    pref[t] = sm[t] - cnt[t];
    const int node = nbase + t;
    if (node < N) {
        rowptr[node] = gbase + pref[t];
        dis[node] = rsqrtf((float)cnt[t] + 1.0f);
    }
    __syncthreads();
    for (int i = t; i < ecnt; i += 256) {
        const int p = ep[i];
        const int d = ((unsigned)p) >> 24;
        const int pos = gbase + pref[d] + atomicAdd(&fillc[d], 1);
        col[pos] = p & 0xFFFFFF;
    }
}

// One-time weight pack: W [K][BN] f32 -> hi/lo bf16 in MFMA fragment order.
__global__ __launch_bounds__(256) void pack_w(const float* __restrict__ W,
                                              unsigned short* __restrict__ packH,
                                              unsigned short* __restrict__ packL,
                                              int K, int BN) {
    const int idx = blockIdx.x * blockDim.x + threadIdx.x;
    if (idx >= K * BN) return;
    const int e = idx & 7;
    const int l = (idx >> 3) & 63;
    const int rest = idx >> 9;  // ks*NF + nf
    const int NF = BN >> 4;
    const int nf = rest % NF;
    const int ks = rest / NF;
    const int n = nf * 16 + (l & 15);
    const int k = ks * 32 + ((l >> 4) & 3) * 8 + e;
    const float v = W[(size_t)k * BN + n];
    const unsigned short h = f2bf(v);
    packH[idx] = h;
    packL[idx] = f2bf(v - bf2f(h));
}

// MFMA GEMM (layer 1): f32 A, 4-buffer global_load_lds pipeline, counted
// vmcnt, raw s_barrier. BM=64, BK=32. A consumed as bf16-hi; W hi/lo.
template <int BN, int K>
__global__ __launch_bounds__(256) void gemm_mfma(const float* __restrict__ A,
                                                 const unsigned short* __restrict__ WpH,
                                                 const unsigned short* __restrict__ WpL,
                                                 const float* __restrict__ scale,
                                                 unsigned short* __restrict__ Out,
                                                 int N) {
    constexpr int BM = 64;
    constexpr int NK = K / 32;               // 12
    constexpr int WROWS = (BN == 128) ? 2 : 4;
    constexpr int WCOLS = (BN == 128) ? 2 : 1;
    constexpr int WTM = BM / WROWS;
    constexpr int MF = WTM / 16;
    constexpr int NFW = (BN / WCOLS) / 16;
    constexpr int NFB = BN / 16;

    __shared__ float AsF[4][4][16][32];  // 32 KB

    const int t = threadIdx.x;
    const int wid = t >> 6, lane = t & 63;
    const int wr = wid / WCOLS, wc = wid % WCOLS;
    const int r0 = blockIdx.x * BM;

    const int dmarow0 = min(r0 + wid * 16 + (lane >> 3), NN - 1);
    const int dmarow1 = min(r0 + wid * 16 + 8 + (lane >> 3), NN - 1);
    const float* dmap0 = A + (size_t)dmarow0 * K + (lane & 7) * 4;
    const float* dmap1 = A + (size_t)dmarow1 * K + (lane & 7) * 4;

    auto stageA = [&](int buf, int ks) {
        gload_lds16(dmap0 + ks * 32, &AsF[buf][wid][0][0]);
        gload_lds16(dmap1 + ks * 32, &AsF[buf][wid][8][0]);
    };
    auto loadB = [&](int ks, short8* bH, short8* bL) {
#pragma unroll
        for (int n = 0; n < NFW; ++n) {
            const int nfg = wc * NFW + n;
            const int base = ((ks * NFB + nfg) * 64 + lane) * 8;
            bH[n] = *(const short8*)&WpH[base];
            bL[n] = *(const short8*)&WpL[base];
        }
    };

    f32x4 acc[MF][NFW];
#pragma unroll
    for (int m = 0; m < MF; ++m)
#pragma unroll
        for (int n = 0; n < NFW; ++n) acc[m][n] = (f32x4){0.f, 0.f, 0.f, 0.f};

    short8 bHc[NFW], bLc[NFW];
    loadB(0, bHc, bLc);
    stageA(0, 0);
    if (NK > 1) stageA(1, 1);
    if (NK > 2) stageA(2, 2);

#pragma unroll
    for (int ks = 0; ks < NK; ++ks) {
        if (ks == NK - 1) {
            asm volatile("s_waitcnt vmcnt(0)" ::: "memory");
        } else {
            asm volatile("s_waitcnt vmcnt(4)" ::: "memory");
        }
        __builtin_amdgcn_s_barrier();
        short8 bHn[NFW], bLn[NFW];
        if (ks + 1 < NK) loadB(ks + 1, bHn, bLn);
        if (ks + 3 < NK) stageA((ks + 3) & 3, ks + 3);
        const int cur = ks & 3;
#pragma unroll
        for (int m = 0; m < MF; ++m) {
            const int mf = wr * MF + m;
            const float* fp = &AsF[cur][mf][lane & 15][(lane >> 4) * 8];
            const f32x4 f0 = *(const f32x4*)fp;
            const f32x4 f1 = *(const f32x4*)(fp + 4);
            short8 aH;
            aH[0] = (short)f2bf(f0[0]);
            aH[1] = (short)f2bf(f0[1]);
            aH[2] = (short)f2bf(f0[2]);
            aH[3] = (short)f2bf(f0[3]);
            aH[4] = (short)f2bf(f1[0]);
            aH[5] = (short)f2bf(f1[1]);
            aH[6] = (short)f2bf(f1[2]);
            aH[7] = (short)f2bf(f1[3]);
#pragma unroll
            for (int n = 0; n < NFW; ++n) {
                acc[m][n] = __builtin_amdgcn_mfma_f32_16x16x32_bf16(aH, bHc[n], acc[m][n], 0, 0, 0);
                acc[m][n] = __builtin_amdgcn_mfma_f32_16x16x32_bf16(aH, bLc[n], acc[m][n], 0, 0, 0);
            }
        }
        if (ks + 1 < NK) {
#pragma unroll
            for (int n = 0; n < NFW; ++n) {
                bHc[n] = bHn[n];
                bLc[n] = bLn[n];
            }
        }
    }

#pragma unroll
    for (int m = 0; m < MF; ++m) {
        const int row0 = r0 + wr * WTM + m * 16 + ((lane >> 4) << 2);
        float sc[4];
#pragma unroll
        for (int r = 0; r < 4; ++r) sc[r] = (row0 + r < N) ? scale[row0 + r] : 0.f;
#pragma unroll
        for (int n = 0; n < NFW; ++n) {
            const int cn = wc * (NFW * 16) + n * 16 + (lane & 15);
#pragma unroll
            for (int r = 0; r < 4; ++r) {
                if (row0 + r < N)
                    Out[(size_t)(row0 + r) * BN + cn] = f2bf(acc[m][n][r] * sc[r]);
            }
        }
    }
}

// MFMA GEMM (layer 2): bf16 A, counted-vmcnt 4-buffer DMA pipeline.
// 1 DMA/wave/tile. vmcnt: iter0=2, mid=4, last=0 (r24 audit).
template <int BN, int K>
__global__ __launch_bounds__(256) void gemm_mfma_b(const unsigned short* __restrict__ A,
                                                   const unsigned short* __restrict__ WpH,
                                                   const unsigned short* __restrict__ WpL,
                                                   const float* __restrict__ scale,
                                                   unsigned short* __restrict__ Out,
                                                   int N) {
    constexpr int BM = 64;
    constexpr int NK = K / 32;               // 4
    constexpr int WROWS = 4;
    constexpr int WTM = BM / WROWS;          // 16
    constexpr int NFW = BN / 16;             // 4
    constexpr int NFB = BN / 16;

    __shared__ unsigned short AsB[4][4][16][32];  // 16 KB

    const int t = threadIdx.x;
    const int wid = t >> 6, lane = t & 63;
    const int wr = wid;
    const int r0 = blockIdx.x * BM;

    const int dmarow = min(r0 + wid * 16 + (lane >> 2), NN - 1);
    const unsigned short* dmap = A + (size_t)dmarow * K + (lane & 3) * 8;

    auto stageA = [&](int buf, int ks) {
        gload_lds16(dmap + ks * 32, &AsB[buf][wid][0][0]);
    };
    auto loadB = [&](int ks, short8* bH, short8* bL) {
#pragma unroll
        for (int n = 0; n < NFW; ++n) {
            const int base = ((ks * NFB + n) * 64 + lane) * 8;
            bH[n] = *(const short8*)&WpH[base];
            bL[n] = *(const short8*)&WpL[base];
        }
    };

    f32x4 acc[NFW];
#pragma unroll
    for (int n = 0; n < NFW; ++n) acc[n] = (f32x4){0.f, 0.f, 0.f, 0.f};

    short8 bHc[NFW], bLc[NFW];
    loadB(0, bHc, bLc);
    stageA(0, 0);
    if (NK > 1) stageA(1, 1);
    if (NK > 2) stageA(2, 2);

#pragma unroll
    for (int ks = 0; ks < NK; ++ks) {
        if (ks == NK - 1) {
            asm volatile("s_waitcnt vmcnt(0)" ::: "memory");
        } else if (ks == 0) {
            asm volatile("s_waitcnt vmcnt(2)" ::: "memory");
        } else {
            asm volatile("s_waitcnt vmcnt(4)" ::: "memory");
        }
        __builtin_amdgcn_s_barrier();
        short8 bHn[NFW], bLn[NFW];
        if (ks + 1 < NK) loadB(ks + 1, bHn, bLn);
        if (ks + 3 < NK) stageA((ks + 3) & 3, ks + 3);
        const int cur = ks & 3;
        const short8 aH = *(const short8*)&AsB[cur][wr][lane & 15][(lane >> 4) * 8];
#pragma unroll
        for (int n = 0; n < NFW; ++n) {
            acc[n] = __builtin_amdgcn_mfma_f32_16x16x32_bf16(aH, bHc[n], acc[n], 0, 0, 0);
            acc[n] = __builtin_amdgcn_mfma_f32_16x16x32_bf16(aH, bLc[n], acc[n], 0, 0, 0);
        }
        if (ks + 1 < NK) {
#pragma unroll
            for (int n = 0; n < NFW; ++n) {
                bHc[n] = bHn[n];
                bLc[n] = bLn[n];
            }
        }
    }

    const int row0 = r0 + wr * WTM + ((lane >> 4) << 2);
    float sc[4];
#pragma unroll
    for (int r = 0; r < 4; ++r) sc[r] = (row0 + r < N) ? scale[row0 + r] : 0.f;
#pragma unroll
    for (int n = 0; n < NFW; ++n) {
        const int cn = n * 16 + (lane & 15);
#pragma unroll
        for (int r = 0; r < 4; ++r) {
            if (row0 + r < N)
                Out[(size_t)(row0 + r) * BN + cn] = f2bf(acc[n][r] * sc[r]);
        }
    }
}

// CSR gather aggregation over PRE-SCALED bf16 H' (= bf16(dis*h)).
// OB16: store output as bf16 (bit-identical for gemm consumers that
// round A to bf16-hi anyway). Otherwise f32.
// Out[d] = relu( dis[d] * (sum_s H'[s] + H'[d]) + bias )
template <int COLS, bool OB16>
__global__ __launch_bounds__(256) void agg_gather(const int* __restrict__ rowptr,
                                                  const int* __restrict__ col,
                                                  const float* __restrict__ dis,
                                                  const unsigned short* __restrict__ Hs,
                                                  const float* __restrict__ bias,
                                                  void* __restrict__ OutV, int N) {
    constexpr int NPW = (COLS == 128) ? 1 : 2;  // nodes per wave
    constexpr int LPN = 64 / NPW;               // lanes per node group
    constexpr int LPR = COLS / 8;               // lanes per row (bf16x8)
    constexpr int NSG = LPN / LPR;              // 4 edge subgroups
    const int gw = (int)((blockIdx.x * blockDim.x + threadIdx.x) >> 6);
    const int lane = threadIdx.x & 63;
    const int sub = lane / LPN;    // node within wave
    const int nl = lane % LPN;     // lane within node group
    const int esub = nl / LPR;     // edge subgroup 0..3
    const int sl = nl % LPR;       // 8-col group within row
    const int node = gw * NPW + sub;
    const int lgbase = sub * LPN;

    float acc[8];
#pragma unroll
    for (int k = 0; k < 8; ++k) acc[k] = 0.f;

    int base = 0, len = 0;
    const int nodec = (node < N) ? node : 0;
    if (node < N) {
        base = rowptr[node];
        len = rowptr[node + 1] - base;
    }

    for (int j0 = 0; j0 < len; j0 += LPN) {
        const int remain = min(LPN, len - j0);
        const int sidx = (nl < remain) ? col[base + j0 + nl] : nodec;
        const int qtr = (remain + NSG - 1) / NSG;  // uniform trip count
        const int off = esub * qtr;
        int u = 0;
        for (; u + 8 <= qtr; u += 8) {
            u16x8 hv[8];
            float wv[8];
#pragma unroll
            for (int b = 0; b < 8; ++b) {
                const int idx = off + u + b;
                const int s = __shfl(sidx, lgbase + idx);
                wv[b] = (idx < remain) ? 1.f : 0.f;
                hv[b] = *(const u16x8*)(Hs + (size_t)s * COLS + sl * 8);
            }
#pragma unroll
            for (int b = 0; b < 8; ++b)
#pragma unroll
                for (int k = 0; k < 8; ++k)
                    acc[k] = fmaf(bf2f(hv[b][k]), wv[b], acc[k]);
        }
        for (; u + 4 <= qtr; u += 4) {
            u16x8 hv[4];
            float wv[4];
#pragma unroll
            for (int b = 0; b < 4; ++b) {
                const int idx = off + u + b;
                const int s = __shfl(sidx, lgbase + idx);
                wv[b] = (idx < remain) ? 1.f : 0.f;
                hv[b] = *(const u16x8*)(Hs + (size_t)s * COLS + sl * 8);
            }
#pragma unroll
            for (int b = 0; b < 4; ++b)
#pragma unroll
                for (int k = 0; k < 8; ++k)
                    acc[k] = fmaf(bf2f(hv[b][k]), wv[b], acc[k]);
        }
        for (; u < qtr; ++u) {
            const int idx = off + u;
            const int s = __shfl(sidx, lgbase + idx);
            const float w = (idx < remain) ? 1.f : 0.f;
            const u16x8 hv = *(const u16x8*)(Hs + (size_t)s * COLS + sl * 8);
#pragma unroll
            for (int k = 0; k < 8; ++k)
                acc[k] = fmaf(bf2f(hv[k]), w, acc[k]);
        }
    }

#pragma unroll
    for (int k = 0; k < 8; ++k) {
        acc[k] += __shfl_xor(acc[k], LPR);
        acc[k] += __shfl_xor(acc[k], 2 * LPR);
    }

    if (node < N && esub == 0) {
        const float dd = dis[node];
        const u16x8 hsb = *(const u16x8*)(Hs + (size_t)node * COLS + sl * 8);
        float o[8];
#pragma unroll
        for (int k = 0; k < 8; ++k)
            o[k] = fmaxf(fmaf(acc[k] + bf2f(hsb[k]), dd, bias[sl * 8 + k]), 0.f);
        if (OB16) {
            u16x8 ob;
#pragma unroll
            for (int k = 0; k < 8; ++k) ob[k] = f2bf(o[k]);
            *(u16x8*)((unsigned short*)OutV + (size_t)node * COLS + sl * 8) = ob;
        } else {
            float* Out = (float*)OutV;
            f32x4 o0, o1;
#pragma unroll
            for (int k = 0; k < 4; ++k) {
                o0[k] = o[k];
                o1[k] = o[k + 4];
            }
            *(f32x4*)(Out + (size_t)node * COLS + sl * 8) = o0;
            *(f32x4*)(Out + (size_t)node * COLS + sl * 8 + 4) = o1;
        }
    }
}

// mean-pool prep: wave = 32 consecutive rows, lane = column.
__global__ __launch_bounds__(256) void pool_kernel(const float* __restrict__ H,
                                                   const int* __restrict__ batch,
                                                   float* __restrict__ pooled,
                                                   float* __restrict__ cnt, int N) {
    const int c = threadIdx.x & 63;
    const int w = threadIdx.x >> 6;          // wave 0..3
    const int row0 = blockIdx.x * 128 + w * 32;
    if (row0 >= N) return;
    const int nr = min(32, N - row0);

    float v[32];
    int b[32];
#pragma unroll
    for (int i = 0; i < 32; ++i) {
        const int r = row0 + i;
        if (i < nr) {
            v[i] = H[(size_t)r * 64 + c];
            b[i] = batch[r];
        } else {
            v[i] = 0.f;
            b[i] = -1;
        }
    }
    int cur = b[0];
    float sum = 0.f, csum = 0.f;
#pragma unroll
    for (int i = 0; i < 32; ++i) {
        if (i < nr) {
            if (b[i] != cur) {
                atomicAdd(&pooled[cur * 64 + c], sum);
                if (c == 0) atomicAdd(&cnt[cur], csum);
                cur = b[i];
                sum = 0.f;
                csum = 0.f;
            }
            sum += v[i];
            csum += 1.f;
        }
    }
    atomicAdd(&pooled[cur * 64 + c], sum);
    if (c == 0) atomicAdd(&cnt[cur], csum);
}

__global__ __launch_bounds__(256) void final_kernel(const float* __restrict__ pooled,
                                                    const float* __restrict__ cnt,
                                                    const float* __restrict__ Wlin,
                                                    const float* __restrict__ blin,
                                                    float* __restrict__ out) {
    const int t = threadIdx.x;
    const int g = t >> 1, o = t & 1;
    const float inv = 1.0f / fmaxf(cnt[g], 1.0f);
    float s = 0.f;
#pragma unroll
    for (int j = 0; j < 64; ++j) s = fmaf(pooled[g * 64 + j], Wlin[j * 2 + o], s);
    out[t] = s * inv + blin[o];
}

extern "C" void kernel_launch(void* const* d_in, const int* in_sizes, int n_in,
                              void* d_out, int out_size, void* d_ws, size_t ws_size,
                              hipStream_t stream) {
    const float* x     = (const float*)d_in[0];
    const int*   edge  = (const int*)d_in[1];
    const int*   batch = (const int*)d_in[2];
    const float* W1    = (const float*)d_in[3];
    const float* b1    = (const float*)d_in[4];
    const float* W2    = (const float*)d_in[5];
    const float* b2    = (const float*)d_in[6];
    const float* Wlin  = (const float*)d_in[7];
    const float* blin  = (const float*)d_in[8];
    float* out = (float*)d_out;

    const int N = NN;
    const int E = in_sizes[1] / 2;
    const int* src = edge;
    const int* dst = edge + E;

    char* ws = (char*)d_ws;
    size_t off = 0;
    auto alloc = [&](size_t bytes) -> void* {
        void* p = ws + off;
        off += (bytes + 511) & ~(size_t)511;
        return p;
    };
    float* dis    = (float*)alloc((size_t)N * 4);
    int*   rowptr = (int*)alloc((size_t)(N + 1) * 4);
    int*   bcnt   = (int*)alloc((size_t)NBUK * 4);
    int*   bbase  = (int*)alloc((size_t)(NBUK + 1) * 4);
    int*   col    = (int*)alloc((size_t)E * 4);                 // 6.4 MB
    int*   pairs  = (int*)alloc((size_t)NBUK * BCAP * 4);       // 9.6 MB (packed)
    unsigned short* w1h = (unsigned short*)alloc((size_t)384 * 128 * 2);
    unsigned short* w1l = (unsigned short*)alloc((size_t)384 * 128 * 2);
    unsigned short* w2h = (unsigned short*)alloc((size_t)128 * 64 * 2);
    unsigned short* w2l = (unsigned short*)alloc((size_t)128 * 64 * 2);
    unsigned short* h1bf   = (unsigned short*)alloc((size_t)N * 128 * 2);  // 25.6 MB
    unsigned short* agg1bf = (unsigned short*)alloc((size_t)N * 128 * 2);  // 25.6 MB
    float* pooled = (float*)alloc((size_t)NG * 64 * 4);
    float* cnt    = (float*)alloc((size_t)NG * 4);
    // layer-2 reuse: h2bf in h1bf region (h1bf dead after agg<128>);
    // agg2 (f32, 25.6MB) in agg1bf region (agg1bf dead after gemm2).
    unsigned short* h2bf = h1bf;
    float* agg2 = (float*)agg1bf;

    // zero bcnt/pooled/cnt
    init_kernel<<<(NG * 64 + 255) / 256, 256, 0, stream>>>(bcnt, pooled, cnt);

    // weight packing (tiny, once per call)
    pack_w<<<(384 * 128 + 255) / 256, 256, 0, stream>>>(W1, w1h, w1l, 384, 128);
    pack_w<<<(128 * 64 + 255) / 256, 256, 0, stream>>>(W2, w2h, w2l, 128, 64);

    // CSR build via bucketed counting sort (packed pairs)
    bucket_scatter<<<512, 256, 0, stream>>>(src, dst, bcnt, pairs, E);
    bucket_scan<<<1, 512, 0, stream>>>(bcnt, bbase, rowptr, N, E);
    bucket_build<<<NBUK, 256, 0, stream>>>(pairs, bcnt, bbase, rowptr, dis, col, N);

    const int gblocks = (N + 63) / 64;  // 1563
    // layer 1 (gemm writes dis-prescaled bf16 h1'; agg1 stored bf16)
    gemm_mfma<128, 384><<<gblocks, 256, 0, stream>>>(x, w1h, w1l, dis, h1bf, N);
    agg_gather<128, true><<<(N + 3) / 4, 256, 0, stream>>>(rowptr, col, dis, h1bf, b1,
                                                           (void*)agg1bf, N);

    // layer 2 (bf16-A gemm reads agg1bf; h2' bf16; agg2 f32)
    gemm_mfma_b<64, 128><<<gblocks, 256, 0, stream>>>(agg1bf, w2h, w2l, dis, h2bf, N);
    agg_gather<64, false><<<(N + 7) / 8, 256, 0, stream>>>(rowptr, col, dis, h2bf, b2,
                                                           (void*)agg2, N);

    // pool + head
    pool_kernel<<<(N + 127) / 128, 256, 0, stream>>>(agg2, batch, pooled, cnt, N);
    final_kernel<<<1, 256, 0, stream>>>(pooled, cnt, Wlin, blin, out);
}